// Round 16
// baseline (940.008 us; speedup 1.0000x reference)
//
#include <hip/hip_runtime.h>

// RNN on MI355X: h_{t+1} = tanh(table[X[:,t]] + h_t @ W_hh), T=256, B=1024, H=512.
// Round 16: r15 (611us, static-address 2x-unrolled ping-pong) + WL 4->2 sets,
// stream 6->8 sets. This is r13's shift, which spilled (~10 regs -> MFMA-chain
// scratch serialization) under r11's runtime-pointer structure; r15's static
// addressing freed those registers, so the shift should now fit spill-free.
//   sets 0..5  -> AGPR (48 regs/wave, pinned "+a")
//   sets 6..13 -> streamed from L2 (256 KB/CU/step, sa/sb consume-then-load)
//   sets 14,15 -> WL LDS (64 KB, staged once)
// LDS/step 400->336 KB (~3.9k cyc); stream 256 KB under the LDS wall.
// 16 waves x 32 cols, 1024 thr, 1 lgkm-barrier/step.
// f16 single-term MFMA builtins: absmax exactly 0.0078125 expected.

typedef __attribute__((ext_vector_type(4))) float f32x4;
typedef __attribute__((ext_vector_type(8))) _Float16 f16x8;

#define T_ 256
#define E_ 128
#define H_ 512
#define V_ 115

__device__ __forceinline__ float tanh_fast(float x) {
  float e = __builtin_exp2f(x * 2.8853900817779268f);  // 2*log2(e)
  return 1.0f - 2.0f * __builtin_amdgcn_rcpf(e + 1.0f);
}

// lgkm-only barrier: global (W-stream, X, gather) loads stay in flight.
__device__ __forceinline__ void sync_lgkm() {
  asm volatile("s_waitcnt lgkmcnt(0)" ::: "memory");
  __builtin_amdgcn_s_barrier();
}

// table[v][h] = b_h[h] + sum_e W_emb[v][e] * W_xh[e][h]   (115 x 512, f32)
__global__ void prep_table(const float* __restrict__ Wemb, const float* __restrict__ Wxh,
                           const float* __restrict__ bh, float* __restrict__ Txh) {
  int v = blockIdx.x;
  int h = threadIdx.x;
  float s = bh[h];
  const float* we = Wemb + v * E_;
#pragma unroll 8
  for (int e = 0; e < E_; ++e) s += we[e] * Wxh[e * H_ + h];
  Txh[v * H_ + h] = s;
}

// Wf layout (f16): frag (nb=n>>4, kc=k>>5) is a contiguous 1KB block of 64
// lanes x 16B; lane (lg*16+lm) holds col n=nb*16+lm, k=kc*32+lg*8..+8.
__global__ void prep_wf(const float* __restrict__ Whh, _Float16* __restrict__ Wf) {
  int idx = blockIdx.x * 256 + threadIdx.x;  // 512*512
  int k = idx >> 9, n = idx & 511;
  float w = Whh[k * H_ + n];
  int nb = n >> 4, lm = n & 15, kc = k >> 5, lg = (k >> 3) & 3, kk = k & 7;
  Wf[(((nb * 16 + kc) * 4 + lg) * 16 + lm) * 8 + kk] = (_Float16)w;
}

// W frag (f, set s) for wave with col-block base nb0 (f in {0,1})
#define WG(f, s) (((const f16x8*)Wf)[(((nb0 + (f)) * 16 + (s)) << 6) + lane])

// AGPR-resident W: sets 0..5 x 2 frags = 48 AGPRs/wave, pinned once.
#define DECL2(s) f16x8 W##s##_0 = WG(0, s), W##s##_1 = WG(1, s);
#define PIN2(s)  asm volatile("" : "+a"(W##s##_0), "+a"(W##s##_1));

#define MMB(ac, a8, wv) \
  ac = __builtin_amdgcn_mfma_f32_16x16x32_f16(a8, wv, ac, 0, 0, 0);

// AR = static shared array (compile-time base -> ds offset immediates)
#define RSET(AR, s) {                                               \
  f16x8 a8 = *(const f16x8*)(AR + (s) * 512 + lane * 8);            \
  MMB(acc0, a8, W##s##_0) MMB(acc1, a8, W##s##_1) }

#define SSET(AR, buf, s) {                                          \
  f16x8 a8 = *(const f16x8*)(AR + (s) * 512 + lane * 8);            \
  MMB(acc0, a8, buf[0]) MMB(acc1, a8, buf[1]) }
#define SLOAD(buf, s) { buf[0] = WG(0, s); buf[1] = WG(1, s); }

// LDS-resident sets 14..15: WL block bi = w*4 + j*2 + f (1 KB each)
#define LSET(AR, j) {                                               \
  f16x8 a8 = *(const f16x8*)(AR + (14 + (j)) * 512 + lane * 8);     \
  const f16x8* wp = (const f16x8*)WL + ((w * 4 + (j) * 2) << 6) + lane; \
  f16x8 q0 = wp[0], q1 = wp[64];                                    \
  MMB(acc0, a8, q0) MMB(acc1, a8, q1) }

// tanh + scatter new h into AW (A-frag layout); no global stores.
#define EPI(AW, f) {                                                \
  int n = w * 32 + (f) * 16 + lm;                                   \
  int bidx = (n >> 5) * 512 + ((n >> 3) & 3) * 128 + (n & 7);       \
  _Pragma("unroll")                                                 \
  for (int r = 0; r < 4; ++r) {                                     \
    float hv = tanh_fast(acc##f[r]);                                \
    AW[bidx + (lg * 4 + r) * 8] = (_Float16)hv;                     \
  } }

// One full RNN step: read AR, write AW, prefetch X index for step TN.
#define STEP(AR, AW, TN)                                            \
  {                                                                 \
    f32x4 acc0, acc1;                                               \
    {                                                               \
      const float* g0 = txl + (vpack & 255) * H_;                   \
      const float* g1 = txl + ((vpack >> 8) & 255) * H_;            \
      const float* g2 = txl + ((vpack >> 16) & 255) * H_;           \
      const float* g3 = txl + ((unsigned)vpack >> 24) * H_;         \
      acc0[0]=g0[0];  acc0[1]=g1[0];  acc0[2]=g2[0];  acc0[3]=g3[0];\
      acc1[0]=g0[16]; acc1[1]=g1[16]; acc1[2]=g2[16]; acc1[3]=g3[16];\
    }                                                               \
    {                                                               \
      int tn = (TN) & (T_ - 1);                                     \
      vpack = (xrow[tn] & 255) | ((xrow[T_ + tn] & 255) << 8) |     \
              ((xrow[2 * T_ + tn] & 255) << 16) |                   \
              ((xrow[3 * T_ + tn] & 255) << 24);                    \
    }                                                               \
    SSET(AR, sa, 6)   SLOAD(sa, 8)                                  \
    SSET(AR, sb, 7)   SLOAD(sb, 9)                                  \
    RSET(AR, 0) RSET(AR, 1) RSET(AR, 2)                             \
    RSET(AR, 3) RSET(AR, 4) RSET(AR, 5)                             \
    SSET(AR, sa, 8)   SLOAD(sa, 10)                                 \
    SSET(AR, sb, 9)   SLOAD(sb, 11)                                 \
    LSET(AR, 0)                                                     \
    SSET(AR, sa, 10)  SLOAD(sa, 12)                                 \
    SSET(AR, sb, 11)  SLOAD(sb, 13)                                 \
    LSET(AR, 1)                                                     \
    SSET(AR, sa, 12)  SLOAD(sa, 6)                                  \
    SSET(AR, sb, 13)  SLOAD(sb, 7)                                  \
    EPI(AW, 0) EPI(AW, 1)                                           \
    sync_lgkm();                                                    \
  }

__global__ __launch_bounds__(1024, 4)
void rnn_main(const int* __restrict__ X, const float* __restrict__ Txh,
              const _Float16* __restrict__ Wf, const float* __restrict__ Why,
              const float* __restrict__ by, float* __restrict__ out) {
  __shared__ _Float16 Ah0[16 * H_];     // 16 KB: h even steps (A-frag layout)
  __shared__ _Float16 Ah1[16 * H_];     // 16 KB: h odd steps
  __shared__ _Float16 WL[32768];        // 64 KB: W sets 14..15, all 16 waves

  const int tid = threadIdx.x;
  const int lane = tid & 63;
  const int w = tid >> 6;          // wave 0..15; owns cols [w*32, w*32+32)
  const int nb0 = w * 2;
  const int r0 = blockIdx.x * 16;
  const int lm = lane & 15;
  const int lg = lane >> 4;

  // h0 = 0 (Ah0 only; Ah1 is written before first read)
  for (int i = tid; i < 16 * H_ / 2; i += 1024) ((int*)Ah0)[i] = 0;
  // Stage W sets 14..15 into WL (one time, 64 KB). bi = w*4 + j*2 + f.
  for (int i = tid; i < 4096; i += 1024) {
    int bi = i >> 6, ln = i & 63;
    int w8 = bi >> 2, rem = bi & 3, j = rem >> 1, f = rem & 1;
    int nb = w8 * 2 + f;
    ((f16x8*)WL)[(bi << 6) + ln] =
        ((const f16x8*)Wf)[((nb * 16 + 14 + j) << 6) + ln];
  }

  // AGPR-resident W: sets 0..5 -> 48 AGPRs/wave, loaded once, pinned.
  DECL2(0) DECL2(1) DECL2(2) DECL2(3) DECL2(4) DECL2(5)
  PIN2(0) PIN2(1) PIN2(2) PIN2(3) PIN2(4) PIN2(5)

  // Prime the stream double-buffer: sa <- set 6, sb <- set 7.
  f16x8 sa[2], sb[2];
  SLOAD(sa, 6)
  SLOAD(sb, 7)

  // per-lane loop-invariant bases
  const float* txl = Txh + w * 32 + lm;            // gather base
  const int* xrow = X + (r0 + lg * 4) * T_;        // 4 X rows at imm offsets

  // X indices for t=0, packed 4-per-reg (vocab < 256)
  int vpack = (xrow[0] & 255) | ((xrow[T_] & 255) << 8) |
              ((xrow[2 * T_] & 255) << 16) | ((xrow[3 * T_] & 255) << 24);

  __syncthreads();

  for (int t = 0; t < T_; t += 2) {
    STEP(Ah0, Ah1, t + 1)   // even step: read Ah0, write Ah1
    STEP(Ah1, Ah0, t + 2)   // odd step:  read Ah1, write Ah0
  }

  __syncthreads();  // belt & braces before logits

  // h_T is in Ah0 (T_ even). logits = h_T @ W_hy + b_y.
  for (int idx = tid; idx < 16 * V_; idx += 1024) {
    int m = idx / V_, v = idx - m * V_;
    float s = by[v];
#pragma unroll 8
    for (int k = 0; k < H_; ++k) {
      float hk = (float)Ah0[(k >> 5) * 512 + ((k >> 3) & 3) * 128 + (k & 7) + m * 8];
      s += hk * Why[k * V_ + v];
    }
    out[(r0 + m) * V_ + v] = s;
  }
}

extern "C" void kernel_launch(void* const* d_in, const int* in_sizes, int n_in,
                              void* d_out, int out_size, void* d_ws, size_t ws_size,
                              hipStream_t stream) {
  const int* X = (const int*)d_in[0];         // [1024,256] int32
  const float* Wemb = (const float*)d_in[1];  // [115,128]
  const float* Wxh = (const float*)d_in[2];   // [128,512]
  const float* Whh = (const float*)d_in[3];   // [512,512]
  const float* bh = (const float*)d_in[4];    // [512]
  const float* Why = (const float*)d_in[5];   // [512,115]
  const float* by = (const float*)d_in[6];    // [115]
  float* out = (float*)d_out;                 // [1024,115]

  char* ws = (char*)d_ws;
  float* Txh = (float*)ws;                        // 235,520 B
  _Float16* Wf = (_Float16*)(ws + 256 * 1024);    // 512 KB

  prep_table<<<dim3(V_), dim3(H_), 0, stream>>>(Wemb, Wxh, bh, Txh);
  prep_wf<<<dim3(1024), dim3(256), 0, stream>>>(Whh, Wf);
  rnn_main<<<dim3(64), dim3(1024), 0, stream>>>(X, Txh, Wf, Why, by, out);
}

// Round 17
// 881.021 us; speedup vs baseline: 1.0670x; 1.0670x over previous
//
#include <hip/hip_runtime.h>

// RNN on MI355X: h_{t+1} = tanh(table[X[:,t]] + h_t @ W_hh), T=256, B=1024, H=512.
// Round 17: r15 (611us) + two cheap-direction moves. r16 proved the W-source
// cost hierarchy AGPR >> LDS > stream (stream has ~200-300cyc exposed latency
// per extra rotation pair + L2 contention) -> never grow stream again.
//  1. +1 AGPR set: sets 0..6 resident (56 AGPRs), WL 13..15 (96 KB), stream
//     7..12 (6 sets, SAME depth/shape as r15's proven rotation).
//  2. Cross-barrier xh refill (r8-proven): gather for t+1 issues into dead acc
//     regs after EPI, flies over the barrier -> no step-head L2 stall.
// 16 waves x 32 cols, 1024 thr, static Ah0/Ah1 2x-unrolled ping-pong,
// 1 lgkm-barrier/step. f16 single-term MFMA: absmax exactly 0.0078125.

typedef __attribute__((ext_vector_type(4))) float f32x4;
typedef __attribute__((ext_vector_type(8))) _Float16 f16x8;

#define T_ 256
#define E_ 128
#define H_ 512
#define V_ 115

__device__ __forceinline__ float tanh_fast(float x) {
  float e = __builtin_exp2f(x * 2.8853900817779268f);  // 2*log2(e)
  return 1.0f - 2.0f * __builtin_amdgcn_rcpf(e + 1.0f);
}

// lgkm-only barrier: global (W-stream, X, gather) loads stay in flight.
__device__ __forceinline__ void sync_lgkm() {
  asm volatile("s_waitcnt lgkmcnt(0)" ::: "memory");
  __builtin_amdgcn_s_barrier();
}

// table[v][h] = b_h[h] + sum_e W_emb[v][e] * W_xh[e][h]   (115 x 512, f32)
__global__ void prep_table(const float* __restrict__ Wemb, const float* __restrict__ Wxh,
                           const float* __restrict__ bh, float* __restrict__ Txh) {
  int v = blockIdx.x;
  int h = threadIdx.x;
  float s = bh[h];
  const float* we = Wemb + v * E_;
#pragma unroll 8
  for (int e = 0; e < E_; ++e) s += we[e] * Wxh[e * H_ + h];
  Txh[v * H_ + h] = s;
}

// Wf layout (f16): frag (nb=n>>4, kc=k>>5) is a contiguous 1KB block of 64
// lanes x 16B; lane (lg*16+lm) holds col n=nb*16+lm, k=kc*32+lg*8..+8.
__global__ void prep_wf(const float* __restrict__ Whh, _Float16* __restrict__ Wf) {
  int idx = blockIdx.x * 256 + threadIdx.x;  // 512*512
  int k = idx >> 9, n = idx & 511;
  float w = Whh[k * H_ + n];
  int nb = n >> 4, lm = n & 15, kc = k >> 5, lg = (k >> 3) & 3, kk = k & 7;
  Wf[(((nb * 16 + kc) * 4 + lg) * 16 + lm) * 8 + kk] = (_Float16)w;
}

// W frag (f, set s) for wave with col-block base nb0 (f in {0,1})
#define WG(f, s) (((const f16x8*)Wf)[(((nb0 + (f)) * 16 + (s)) << 6) + lane])

// AGPR-resident W: sets 0..6 x 2 frags = 56 AGPRs/wave, pinned once.
#define DECL2(s) f16x8 W##s##_0 = WG(0, s), W##s##_1 = WG(1, s);
#define PIN2(s)  asm volatile("" : "+a"(W##s##_0), "+a"(W##s##_1));

#define MMB(ac, a8, wv) \
  ac = __builtin_amdgcn_mfma_f32_16x16x32_f16(a8, wv, ac, 0, 0, 0);

// AR = static shared array (compile-time base -> ds offset immediates)
#define RSET(AR, s) {                                               \
  f16x8 a8 = *(const f16x8*)(AR + (s) * 512 + lane * 8);            \
  MMB(acc0, a8, W##s##_0) MMB(acc1, a8, W##s##_1) }

#define SSET(AR, buf, s) {                                          \
  f16x8 a8 = *(const f16x8*)(AR + (s) * 512 + lane * 8);            \
  MMB(acc0, a8, buf[0]) MMB(acc1, a8, buf[1]) }
#define SLOAD(buf, s) { buf[0] = WG(0, s); buf[1] = WG(1, s); }

// LDS-resident sets 13..15: WL block bi = w*6 + j*2 + f (1 KB each)
#define LSET(AR, j) {                                               \
  f16x8 a8 = *(const f16x8*)(AR + (13 + (j)) * 512 + lane * 8);     \
  const f16x8* wp = (const f16x8*)WL + ((w * 6 + (j) * 2) << 6) + lane; \
  f16x8 q0 = wp[0], q1 = wp[64];                                    \
  MMB(acc0, a8, q0) MMB(acc1, a8, q1) }

// tanh + scatter new h into AW (A-frag layout); no global stores.
#define EPI(AW, f) {                                                \
  int n = w * 32 + (f) * 16 + lm;                                   \
  int bidx = (n >> 5) * 512 + ((n >> 3) & 3) * 128 + (n & 7);       \
  _Pragma("unroll")                                                 \
  for (int r = 0; r < 4; ++r) {                                     \
    float hv = tanh_fast(acc##f[r]);                                \
    AW[bidx + (lg * 4 + r) * 8] = (_Float16)hv;                     \
  } }

// One full RNN step: MFMAs on acc (= xh + h@W), EPI, then REFILL acc with
// next step's xh (loads fly over the barrier). vpack loads at head.
#define STEP(AR, AW, TN)                                            \
  {                                                                 \
    {                                                               \
      int tn = (TN) & (T_ - 1);                                     \
      vpack = (xrow[tn] & 255) | ((xrow[T_ + tn] & 255) << 8) |     \
              ((xrow[2 * T_ + tn] & 255) << 16) |                   \
              ((xrow[3 * T_ + tn] & 255) << 24);                    \
    }                                                               \
    SSET(AR, sa, 7)   SLOAD(sa, 9)                                  \
    SSET(AR, sb, 8)   SLOAD(sb, 10)                                 \
    RSET(AR, 0) RSET(AR, 1) RSET(AR, 2) RSET(AR, 3)                 \
    RSET(AR, 4) RSET(AR, 5) RSET(AR, 6)                             \
    SSET(AR, sa, 9)   SLOAD(sa, 11)                                 \
    SSET(AR, sb, 10)  SLOAD(sb, 12)                                 \
    LSET(AR, 0)                                                     \
    SSET(AR, sa, 11)  SLOAD(sa, 7)                                  \
    SSET(AR, sb, 12)  SLOAD(sb, 8)                                  \
    LSET(AR, 1) LSET(AR, 2)                                         \
    EPI(AW, 0) EPI(AW, 1)                                           \
    {                                                               \
      const float* g0 = txl + (vpack & 255) * H_;                   \
      const float* g1 = txl + ((vpack >> 8) & 255) * H_;            \
      const float* g2 = txl + ((vpack >> 16) & 255) * H_;           \
      const float* g3 = txl + ((unsigned)vpack >> 24) * H_;         \
      acc0[0]=g0[0];  acc0[1]=g1[0];  acc0[2]=g2[0];  acc0[3]=g3[0];\
      acc1[0]=g0[16]; acc1[1]=g1[16]; acc1[2]=g2[16]; acc1[3]=g3[16];\
    }                                                               \
    sync_lgkm();                                                    \
  }

__global__ __launch_bounds__(1024, 4)
void rnn_main(const int* __restrict__ X, const float* __restrict__ Txh,
              const _Float16* __restrict__ Wf, const float* __restrict__ Why,
              const float* __restrict__ by, float* __restrict__ out) {
  __shared__ _Float16 Ah0[16 * H_];     // 16 KB: h even steps (A-frag layout)
  __shared__ _Float16 Ah1[16 * H_];     // 16 KB: h odd steps
  __shared__ _Float16 WL[49152];        // 96 KB: W sets 13..15, all 16 waves

  const int tid = threadIdx.x;
  const int lane = tid & 63;
  const int w = tid >> 6;          // wave 0..15; owns cols [w*32, w*32+32)
  const int nb0 = w * 2;
  const int r0 = blockIdx.x * 16;
  const int lm = lane & 15;
  const int lg = lane >> 4;

  // h0 = 0 (Ah0 only; Ah1 is written before first read)
  for (int i = tid; i < 16 * H_ / 2; i += 1024) ((int*)Ah0)[i] = 0;
  // Stage W sets 13..15 into WL (one time, 96 KB). bi = w*6 + j*2 + f.
  for (int i = tid; i < 6144; i += 1024) {
    int bi = i >> 6, ln = i & 63;
    int w8 = bi / 6, rem = bi - w8 * 6, j = rem >> 1, f = rem & 1;
    int nb = w8 * 2 + f;
    ((f16x8*)WL)[(bi << 6) + ln] =
        ((const f16x8*)Wf)[((nb * 16 + 13 + j) << 6) + ln];
  }

  // AGPR-resident W: sets 0..6 -> 56 AGPRs/wave, loaded once, pinned.
  DECL2(0) DECL2(1) DECL2(2) DECL2(3) DECL2(4) DECL2(5) DECL2(6)
  PIN2(0) PIN2(1) PIN2(2) PIN2(3) PIN2(4) PIN2(5) PIN2(6)

  // Prime the stream double-buffer: sa <- set 7, sb <- set 8.
  f16x8 sa[2], sb[2];
  SLOAD(sa, 7)
  SLOAD(sb, 8)

  // per-lane loop-invariant bases
  const float* txl = Txh + w * 32 + lm;            // gather base
  const int* xrow = X + (r0 + lg * 4) * T_;        // 4 X rows at imm offsets

  // xh for t=0 straight into acc; vpack then used for t+1 within each STEP.
  int vpack = (xrow[0] & 255) | ((xrow[T_] & 255) << 8) |
              ((xrow[2 * T_] & 255) << 16) | ((xrow[3 * T_] & 255) << 24);
  f32x4 acc0, acc1;
  {
    const float* g0 = txl + (vpack & 255) * H_;
    const float* g1 = txl + ((vpack >> 8) & 255) * H_;
    const float* g2 = txl + ((vpack >> 16) & 255) * H_;
    const float* g3 = txl + ((unsigned)vpack >> 24) * H_;
    acc0[0]=g0[0];  acc0[1]=g1[0];  acc0[2]=g2[0];  acc0[3]=g3[0];
    acc1[0]=g0[16]; acc1[1]=g1[16]; acc1[2]=g2[16]; acc1[3]=g3[16];
  }

  __syncthreads();

  for (int t = 0; t < T_; t += 2) {
    STEP(Ah0, Ah1, t + 1)   // even step: read Ah0, write Ah1
    STEP(Ah1, Ah0, t + 2)   // odd step:  read Ah1, write Ah0
  }

  __syncthreads();  // belt & braces before logits

  // h_T is in Ah0 (T_ even). logits = h_T @ W_hy + b_y.
  for (int idx = tid; idx < 16 * V_; idx += 1024) {
    int m = idx / V_, v = idx - m * V_;
    float s = by[v];
#pragma unroll 8
    for (int k = 0; k < H_; ++k) {
      float hk = (float)Ah0[(k >> 5) * 512 + ((k >> 3) & 3) * 128 + (k & 7) + m * 8];
      s += hk * Why[k * V_ + v];
    }
    out[(r0 + m) * V_ + v] = s;
  }
}

extern "C" void kernel_launch(void* const* d_in, const int* in_sizes, int n_in,
                              void* d_out, int out_size, void* d_ws, size_t ws_size,
                              hipStream_t stream) {
  const int* X = (const int*)d_in[0];         // [1024,256] int32
  const float* Wemb = (const float*)d_in[1];  // [115,128]
  const float* Wxh = (const float*)d_in[2];   // [128,512]
  const float* Whh = (const float*)d_in[3];   // [512,512]
  const float* bh = (const float*)d_in[4];    // [512]
  const float* Why = (const float*)d_in[5];   // [512,115]
  const float* by = (const float*)d_in[6];    // [115]
  float* out = (float*)d_out;                 // [1024,115]

  char* ws = (char*)d_ws;
  float* Txh = (float*)ws;                        // 235,520 B
  _Float16* Wf = (_Float16*)(ws + 256 * 1024);    // 512 KB

  prep_table<<<dim3(V_), dim3(H_), 0, stream>>>(Wemb, Wxh, bh, Txh);
  prep_wf<<<dim3(1024), dim3(256), 0, stream>>>(Whh, Wf);
  rnn_main<<<dim3(64), dim3(1024), 0, stream>>>(X, Txh, Wf, Why, by, out);
}

// Round 18
// 701.038 us; speedup vs baseline: 1.3409x; 1.2567x over previous
//
#include <hip/hip_runtime.h>

// RNN on MI355X: h_{t+1} = tanh(table[X[:,t]] + h_t @ W_hh), T=256, B=1024, H=512.
// Round 18: r15 (611us) + ONE change: split X-index LOAD from its PACK.
// vmcnt is an ordered counter: r15 packs X words ~5 instrs after loading them,
// forcing a vmcnt(0)-class drain at every step head that kills the sa/sb
// cross-barrier stream prefetch. Now: raw X words load one step EARLY
// (issue-only, +4 regs); pack at next step's head (loads 1 step old, ~20 newer
// loads outstanding -> compiler can emit a loose vmcnt, prefetch survives).
//   sets 0..5  -> AGPR (48 regs/wave, pinned "+a")      [r15 split untouched]
//   sets 6..11 -> streamed from L2 (sa/sb rotation)
//   sets 12..15-> WL LDS (128 KB, staged once)
// 16 waves x 32 cols, 1024 thr, static Ah0/Ah1 ping-pong, 1 lgkm-barrier/step.
// f16 single-term MFMA builtins: absmax exactly 0.0078125 expected.

typedef __attribute__((ext_vector_type(4))) float f32x4;
typedef __attribute__((ext_vector_type(8))) _Float16 f16x8;

#define T_ 256
#define E_ 128
#define H_ 512
#define V_ 115

__device__ __forceinline__ float tanh_fast(float x) {
  float e = __builtin_exp2f(x * 2.8853900817779268f);  // 2*log2(e)
  return 1.0f - 2.0f * __builtin_amdgcn_rcpf(e + 1.0f);
}

// lgkm-only barrier: global (W-stream, X, gather) loads stay in flight.
__device__ __forceinline__ void sync_lgkm() {
  asm volatile("s_waitcnt lgkmcnt(0)" ::: "memory");
  __builtin_amdgcn_s_barrier();
}

// table[v][h] = b_h[h] + sum_e W_emb[v][e] * W_xh[e][h]   (115 x 512, f32)
__global__ void prep_table(const float* __restrict__ Wemb, const float* __restrict__ Wxh,
                           const float* __restrict__ bh, float* __restrict__ Txh) {
  int v = blockIdx.x;
  int h = threadIdx.x;
  float s = bh[h];
  const float* we = Wemb + v * E_;
#pragma unroll 8
  for (int e = 0; e < E_; ++e) s += we[e] * Wxh[e * H_ + h];
  Txh[v * H_ + h] = s;
}

// Wf layout (f16): frag (nb=n>>4, kc=k>>5) is a contiguous 1KB block of 64
// lanes x 16B; lane (lg*16+lm) holds col n=nb*16+lm, k=kc*32+lg*8..+8.
__global__ void prep_wf(const float* __restrict__ Whh, _Float16* __restrict__ Wf) {
  int idx = blockIdx.x * 256 + threadIdx.x;  // 512*512
  int k = idx >> 9, n = idx & 511;
  float w = Whh[k * H_ + n];
  int nb = n >> 4, lm = n & 15, kc = k >> 5, lg = (k >> 3) & 3, kk = k & 7;
  Wf[(((nb * 16 + kc) * 4 + lg) * 16 + lm) * 8 + kk] = (_Float16)w;
}

// W frag (f, set s) for wave with col-block base nb0 (f in {0,1})
#define WG(f, s) (((const f16x8*)Wf)[(((nb0 + (f)) * 16 + (s)) << 6) + lane])

// AGPR-resident W: sets 0..5 x 2 frags = 48 AGPRs/wave, pinned once.
#define DECL2(s) f16x8 W##s##_0 = WG(0, s), W##s##_1 = WG(1, s);
#define PIN2(s)  asm volatile("" : "+a"(W##s##_0), "+a"(W##s##_1));

#define MMB(ac, a8, wv) \
  ac = __builtin_amdgcn_mfma_f32_16x16x32_f16(a8, wv, ac, 0, 0, 0);

// AR = static shared array (compile-time base -> ds offset immediates)
#define RSET(AR, s) {                                               \
  f16x8 a8 = *(const f16x8*)(AR + (s) * 512 + lane * 8);            \
  MMB(acc0, a8, W##s##_0) MMB(acc1, a8, W##s##_1) }

#define SSET(AR, buf, s) {                                          \
  f16x8 a8 = *(const f16x8*)(AR + (s) * 512 + lane * 8);            \
  MMB(acc0, a8, buf[0]) MMB(acc1, a8, buf[1]) }
#define SLOAD(buf, s) { buf[0] = WG(0, s); buf[1] = WG(1, s); }

// LDS-resident sets 12..15: WL block bi = w*8 + j*2 + f (1 KB each)
#define LSET(AR, j) {                                               \
  f16x8 a8 = *(const f16x8*)(AR + (12 + (j)) * 512 + lane * 8);     \
  const f16x8* wp = (const f16x8*)WL + ((w * 8 + (j) * 2) << 6) + lane; \
  f16x8 q0 = wp[0], q1 = wp[64];                                    \
  MMB(acc0, a8, q0) MMB(acc1, a8, q1) }

// tanh + scatter new h into AW (A-frag layout); no global stores.
#define EPI(AW, f) {                                                \
  int n = w * 32 + (f) * 16 + lm;                                   \
  int bidx = (n >> 5) * 512 + ((n >> 3) & 3) * 128 + (n & 7);       \
  _Pragma("unroll")                                                 \
  for (int r = 0; r < 4; ++r) {                                     \
    float hv = tanh_fast(acc##f[r]);                                \
    AW[bidx + (lg * 4 + r) * 8] = (_Float16)hv;                     \
  } }

// One full RNN step for step t (TN = t+2):
//  a. gather acc with vpack (X[:,t], packed LAST step from 1-step-old raws)
//  b. vpack = pack(raw)  -- raw holds X[:,t+1], loaded at step t-1 (old: no drain)
//  c. issue raw loads for X[:,t+2] (consumed at step t+1's phase b)
#define STEP(AR, AW, TN)                                            \
  {                                                                 \
    f32x4 acc0, acc1;                                               \
    {                                                               \
      const float* g0 = txl + (vpack & 255) * H_;                   \
      const float* g1 = txl + ((vpack >> 8) & 255) * H_;            \
      const float* g2 = txl + ((vpack >> 16) & 255) * H_;           \
      const float* g3 = txl + ((unsigned)vpack >> 24) * H_;         \
      acc0[0]=g0[0];  acc0[1]=g1[0];  acc0[2]=g2[0];  acc0[3]=g3[0];\
      acc1[0]=g0[16]; acc1[1]=g1[16]; acc1[2]=g2[16]; acc1[3]=g3[16];\
    }                                                               \
    vpack = (xq0 & 255) | ((xq1 & 255) << 8) |                      \
            ((xq2 & 255) << 16) | ((xq3 & 255) << 24);              \
    {                                                               \
      int tn = (TN) & (T_ - 1);                                     \
      xq0 = xrow[tn];          xq1 = xrow[T_ + tn];                 \
      xq2 = xrow[2 * T_ + tn]; xq3 = xrow[3 * T_ + tn];             \
    }                                                               \
    SSET(AR, sa, 6)   SLOAD(sa, 8)                                  \
    SSET(AR, sb, 7)   SLOAD(sb, 9)                                  \
    RSET(AR, 0) RSET(AR, 1) RSET(AR, 2)                             \
    RSET(AR, 3) RSET(AR, 4) RSET(AR, 5)                             \
    SSET(AR, sa, 8)   SLOAD(sa, 10)                                 \
    SSET(AR, sb, 9)   SLOAD(sb, 11)                                 \
    LSET(AR, 0)                                                     \
    SSET(AR, sa, 10)  SLOAD(sa, 6)                                  \
    SSET(AR, sb, 11)  SLOAD(sb, 7)                                  \
    LSET(AR, 1) LSET(AR, 2) LSET(AR, 3)                             \
    EPI(AW, 0) EPI(AW, 1)                                           \
    sync_lgkm();                                                    \
  }

__global__ __launch_bounds__(1024, 4)
void rnn_main(const int* __restrict__ X, const float* __restrict__ Txh,
              const _Float16* __restrict__ Wf, const float* __restrict__ Why,
              const float* __restrict__ by, float* __restrict__ out) {
  __shared__ _Float16 Ah0[16 * H_];     // 16 KB: h even steps (A-frag layout)
  __shared__ _Float16 Ah1[16 * H_];     // 16 KB: h odd steps
  __shared__ _Float16 WL[65536];        // 128 KB: W sets 12..15, all 16 waves

  const int tid = threadIdx.x;
  const int lane = tid & 63;
  const int w = tid >> 6;          // wave 0..15; owns cols [w*32, w*32+32)
  const int nb0 = w * 2;
  const int r0 = blockIdx.x * 16;
  const int lm = lane & 15;
  const int lg = lane >> 4;

  // h0 = 0 (Ah0 only; Ah1 is written before first read)
  for (int i = tid; i < 16 * H_ / 2; i += 1024) ((int*)Ah0)[i] = 0;
  // Stage W sets 12..15 into WL (one time, 128 KB). bi = w*8 + j*2 + f.
  for (int i = tid; i < 8192; i += 1024) {
    int bi = i >> 6, ln = i & 63;
    int w8 = bi >> 3, rem = bi & 7, j = rem >> 1, f = rem & 1;
    int nb = w8 * 2 + f;
    ((f16x8*)WL)[(bi << 6) + ln] =
        ((const f16x8*)Wf)[((nb * 16 + 12 + j) << 6) + ln];
  }

  // AGPR-resident W: sets 0..5 -> 48 AGPRs/wave, loaded once, pinned.
  DECL2(0) DECL2(1) DECL2(2) DECL2(3) DECL2(4) DECL2(5)
  PIN2(0) PIN2(1) PIN2(2) PIN2(3) PIN2(4) PIN2(5)

  // Prime the stream double-buffer: sa <- set 6, sb <- set 7.
  f16x8 sa[2], sb[2];
  SLOAD(sa, 6)
  SLOAD(sb, 7)

  // per-lane loop-invariant bases
  const float* txl = Txh + w * 32 + lm;            // gather base
  const int* xrow = X + (r0 + lg * 4) * T_;        // 4 X rows at imm offsets

  // Prologue: vpack = X[:,0]; raw <- X[:,1] (issue-only, packed in STEP t=0).
  int xq0 = xrow[0], xq1 = xrow[T_], xq2 = xrow[2 * T_], xq3 = xrow[3 * T_];
  int vpack = (xq0 & 255) | ((xq1 & 255) << 8) |
              ((xq2 & 255) << 16) | ((xq3 & 255) << 24);
  xq0 = xrow[1]; xq1 = xrow[T_ + 1]; xq2 = xrow[2 * T_ + 1]; xq3 = xrow[3 * T_ + 1];

  __syncthreads();

  for (int t = 0; t < T_; t += 2) {
    STEP(Ah0, Ah1, t + 2)   // even step: read Ah0, write Ah1
    STEP(Ah1, Ah0, t + 3)   // odd step:  read Ah1, write Ah0
  }

  __syncthreads();  // belt & braces before logits

  // h_T is in Ah0 (T_ even). logits = h_T @ W_hy + b_y.
  for (int idx = tid; idx < 16 * V_; idx += 1024) {
    int m = idx / V_, v = idx - m * V_;
    float s = by[v];
#pragma unroll 8
    for (int k = 0; k < H_; ++k) {
      float hk = (float)Ah0[(k >> 5) * 512 + ((k >> 3) & 3) * 128 + (k & 7) + m * 8];
      s += hk * Why[k * V_ + v];
    }
    out[(r0 + m) * V_ + v] = s;
  }
}

extern "C" void kernel_launch(void* const* d_in, const int* in_sizes, int n_in,
                              void* d_out, int out_size, void* d_ws, size_t ws_size,
                              hipStream_t stream) {
  const int* X = (const int*)d_in[0];         // [1024,256] int32
  const float* Wemb = (const float*)d_in[1];  // [115,128]
  const float* Wxh = (const float*)d_in[2];   // [128,512]
  const float* Whh = (const float*)d_in[3];   // [512,512]
  const float* bh = (const float*)d_in[4];    // [512]
  const float* Why = (const float*)d_in[5];   // [512,115]
  const float* by = (const float*)d_in[6];    // [115]
  float* out = (float*)d_out;                 // [1024,115]

  char* ws = (char*)d_ws;
  float* Txh = (float*)ws;                        // 235,520 B
  _Float16* Wf = (_Float16*)(ws + 256 * 1024);    // 512 KB

  prep_table<<<dim3(V_), dim3(H_), 0, stream>>>(Wemb, Wxh, bh, Txh);
  prep_wf<<<dim3(1024), dim3(256), 0, stream>>>(Whh, Wf);
  rnn_main<<<dim3(64), dim3(1024), 0, stream>>>(X, Txh, Wf, Why, by, out);
}

// Round 19
// 610.450 us; speedup vs baseline: 1.5399x; 1.1484x over previous
//
#include <hip/hip_runtime.h>

// RNN on MI355X: h_{t+1} = tanh(table[X[:,t]] + h_t @ W_hh), T=256, B=1024, H=512.
// FINAL (= round 15, 611us, absmax 0.0078125). Rounds 16-18 perturbed this
// structure (WL->stream shift, +AGPR set, X load/pack split) and ALL regressed
// (940/881/701us): the compiled step body is a local optimum; source-level
// reordering degrades the compiler's schedule by more than any modeled gain.
// Structure:
//  - Algebraic collapse: xh[b,t] = (W_emb@W_xh + b_h)[X[b,t]] (115x512 table).
//  - 64 blocks x 16 batch rows (no inter-block sync across 256 seq steps);
//    16 waves x 32 cols, 1024 thr, 4 waves/SIMD.
//  - W_hh^T (f16) per-wave k-sets: 0..5 AGPR-resident (48 AGPRs, pinned;
//    feasible ask -> no spill), 6..11 streamed from L2 (sa/sb rotation whose
//    last issues fly over the barrier), 12..15 in LDS WL (128 KB).
//  - h ping-pong in two STATIC __shared__ arrays (compile-time ds offsets),
//    one lgkm-only barrier per step; h stays f16 in A-frag layout.
//  - acc initialized from the xh gather (MFMA C-operand); logits read h_T
//    straight from LDS. f16 single-term MFMA via builtins.

typedef __attribute__((ext_vector_type(4))) float f32x4;
typedef __attribute__((ext_vector_type(8))) _Float16 f16x8;

#define T_ 256
#define E_ 128
#define H_ 512
#define V_ 115

__device__ __forceinline__ float tanh_fast(float x) {
  float e = __builtin_exp2f(x * 2.8853900817779268f);  // 2*log2(e)
  return 1.0f - 2.0f * __builtin_amdgcn_rcpf(e + 1.0f);
}

// lgkm-only barrier: global (W-stream, X, gather) loads stay in flight.
__device__ __forceinline__ void sync_lgkm() {
  asm volatile("s_waitcnt lgkmcnt(0)" ::: "memory");
  __builtin_amdgcn_s_barrier();
}

// table[v][h] = b_h[h] + sum_e W_emb[v][e] * W_xh[e][h]   (115 x 512, f32)
__global__ void prep_table(const float* __restrict__ Wemb, const float* __restrict__ Wxh,
                           const float* __restrict__ bh, float* __restrict__ Txh) {
  int v = blockIdx.x;
  int h = threadIdx.x;
  float s = bh[h];
  const float* we = Wemb + v * E_;
#pragma unroll 8
  for (int e = 0; e < E_; ++e) s += we[e] * Wxh[e * H_ + h];
  Txh[v * H_ + h] = s;
}

// Wf layout (f16): frag (nb=n>>4, kc=k>>5) is a contiguous 1KB block of 64
// lanes x 16B; lane (lg*16+lm) holds col n=nb*16+lm, k=kc*32+lg*8..+8.
__global__ void prep_wf(const float* __restrict__ Whh, _Float16* __restrict__ Wf) {
  int idx = blockIdx.x * 256 + threadIdx.x;  // 512*512
  int k = idx >> 9, n = idx & 511;
  float w = Whh[k * H_ + n];
  int nb = n >> 4, lm = n & 15, kc = k >> 5, lg = (k >> 3) & 3, kk = k & 7;
  Wf[(((nb * 16 + kc) * 4 + lg) * 16 + lm) * 8 + kk] = (_Float16)w;
}

// W frag (f, set s) for wave with col-block base nb0 (f in {0,1})
#define WG(f, s) (((const f16x8*)Wf)[(((nb0 + (f)) * 16 + (s)) << 6) + lane])

// AGPR-resident W: sets 0..5 x 2 frags = 48 AGPRs/wave, pinned once.
#define DECL2(s) f16x8 W##s##_0 = WG(0, s), W##s##_1 = WG(1, s);
#define PIN2(s)  asm volatile("" : "+a"(W##s##_0), "+a"(W##s##_1));

#define MMB(ac, a8, wv) \
  ac = __builtin_amdgcn_mfma_f32_16x16x32_f16(a8, wv, ac, 0, 0, 0);

// AR = static shared array (compile-time base -> ds offset immediates)
#define RSET(AR, s) {                                               \
  f16x8 a8 = *(const f16x8*)(AR + (s) * 512 + lane * 8);            \
  MMB(acc0, a8, W##s##_0) MMB(acc1, a8, W##s##_1) }

#define SSET(AR, buf, s) {                                          \
  f16x8 a8 = *(const f16x8*)(AR + (s) * 512 + lane * 8);            \
  MMB(acc0, a8, buf[0]) MMB(acc1, a8, buf[1]) }
#define SLOAD(buf, s) { buf[0] = WG(0, s); buf[1] = WG(1, s); }

// LDS-resident sets 12..15: WL block bi = w*8 + j*2 + f (1 KB each)
#define LSET(AR, j) {                                               \
  f16x8 a8 = *(const f16x8*)(AR + (12 + (j)) * 512 + lane * 8);     \
  const f16x8* wp = (const f16x8*)WL + ((w * 8 + (j) * 2) << 6) + lane; \
  f16x8 q0 = wp[0], q1 = wp[64];                                    \
  MMB(acc0, a8, q0) MMB(acc1, a8, q1) }

// tanh + scatter new h into AW (A-frag layout); no global stores.
#define EPI(AW, f) {                                                \
  int n = w * 32 + (f) * 16 + lm;                                   \
  int bidx = (n >> 5) * 512 + ((n >> 3) & 3) * 128 + (n & 7);       \
  _Pragma("unroll")                                                 \
  for (int r = 0; r < 4; ++r) {                                     \
    float hv = tanh_fast(acc##f[r]);                                \
    AW[bidx + (lg * 4 + r) * 8] = (_Float16)hv;                     \
  } }

// One full RNN step: read AR, write AW, prefetch X index for step TN.
#define STEP(AR, AW, TN)                                            \
  {                                                                 \
    f32x4 acc0, acc1;                                               \
    {                                                               \
      const float* g0 = txl + (vpack & 255) * H_;                   \
      const float* g1 = txl + ((vpack >> 8) & 255) * H_;            \
      const float* g2 = txl + ((vpack >> 16) & 255) * H_;           \
      const float* g3 = txl + ((unsigned)vpack >> 24) * H_;         \
      acc0[0]=g0[0];  acc0[1]=g1[0];  acc0[2]=g2[0];  acc0[3]=g3[0];\
      acc1[0]=g0[16]; acc1[1]=g1[16]; acc1[2]=g2[16]; acc1[3]=g3[16];\
    }                                                               \
    {                                                               \
      int tn = (TN) & (T_ - 1);                                     \
      vpack = (xrow[tn] & 255) | ((xrow[T_ + tn] & 255) << 8) |     \
              ((xrow[2 * T_ + tn] & 255) << 16) |                   \
              ((xrow[3 * T_ + tn] & 255) << 24);                    \
    }                                                               \
    SSET(AR, sa, 6)   SLOAD(sa, 8)                                  \
    SSET(AR, sb, 7)   SLOAD(sb, 9)                                  \
    RSET(AR, 0) RSET(AR, 1) RSET(AR, 2)                             \
    RSET(AR, 3) RSET(AR, 4) RSET(AR, 5)                             \
    SSET(AR, sa, 8)   SLOAD(sa, 10)                                 \
    SSET(AR, sb, 9)   SLOAD(sb, 11)                                 \
    LSET(AR, 0) LSET(AR, 1)                                         \
    SSET(AR, sa, 10)  SLOAD(sa, 6)                                  \
    SSET(AR, sb, 11)  SLOAD(sb, 7)                                  \
    LSET(AR, 2) LSET(AR, 3)                                         \
    EPI(AW, 0) EPI(AW, 1)                                           \
    sync_lgkm();                                                    \
  }

__global__ __launch_bounds__(1024, 4)
void rnn_main(const int* __restrict__ X, const float* __restrict__ Txh,
              const _Float16* __restrict__ Wf, const float* __restrict__ Why,
              const float* __restrict__ by, float* __restrict__ out) {
  __shared__ _Float16 Ah0[16 * H_];     // 16 KB: h even steps (A-frag layout)
  __shared__ _Float16 Ah1[16 * H_];     // 16 KB: h odd steps
  __shared__ _Float16 WL[65536];        // 128 KB: W sets 12..15, all 16 waves

  const int tid = threadIdx.x;
  const int lane = tid & 63;
  const int w = tid >> 6;          // wave 0..15; owns cols [w*32, w*32+32)
  const int nb0 = w * 2;
  const int r0 = blockIdx.x * 16;
  const int lm = lane & 15;
  const int lg = lane >> 4;

  // h0 = 0 (Ah0 only; Ah1 is written before first read)
  for (int i = tid; i < 16 * H_ / 2; i += 1024) ((int*)Ah0)[i] = 0;
  // Stage W sets 12..15 into WL (one time, 128 KB). bi = w*8 + j*2 + f.
  for (int i = tid; i < 8192; i += 1024) {
    int bi = i >> 6, ln = i & 63;
    int w8 = bi >> 3, rem = bi & 7, j = rem >> 1, f = rem & 1;
    int nb = w8 * 2 + f;
    ((f16x8*)WL)[(bi << 6) + ln] =
        ((const f16x8*)Wf)[((nb * 16 + 12 + j) << 6) + ln];
  }

  // AGPR-resident W: sets 0..5 -> 48 AGPRs/wave, loaded once, pinned.
  DECL2(0) DECL2(1) DECL2(2) DECL2(3) DECL2(4) DECL2(5)
  PIN2(0) PIN2(1) PIN2(2) PIN2(3) PIN2(4) PIN2(5)

  // Prime the stream double-buffer: sa <- set 6, sb <- set 7.
  f16x8 sa[2], sb[2];
  SLOAD(sa, 6)
  SLOAD(sb, 7)

  // per-lane loop-invariant bases
  const float* txl = Txh + w * 32 + lm;            // gather base
  const int* xrow = X + (r0 + lg * 4) * T_;        // 4 X rows at imm offsets

  // X indices for t=0, packed 4-per-reg (vocab < 256)
  int vpack = (xrow[0] & 255) | ((xrow[T_] & 255) << 8) |
              ((xrow[2 * T_] & 255) << 16) | ((xrow[3 * T_] & 255) << 24);

  __syncthreads();

  for (int t = 0; t < T_; t += 2) {
    STEP(Ah0, Ah1, t + 1)   // even step: read Ah0, write Ah1
    STEP(Ah1, Ah0, t + 2)   // odd step:  read Ah1, write Ah0
  }

  __syncthreads();  // belt & braces before logits

  // h_T is in Ah0 (T_ even). logits = h_T @ W_hy + b_y.
  for (int idx = tid; idx < 16 * V_; idx += 1024) {
    int m = idx / V_, v = idx - m * V_;
    float s = by[v];
#pragma unroll 8
    for (int k = 0; k < H_; ++k) {
      float hk = (float)Ah0[(k >> 5) * 512 + ((k >> 3) & 3) * 128 + (k & 7) + m * 8];
      s += hk * Why[k * V_ + v];
    }
    out[(r0 + m) * V_ + v] = s;
  }
}

extern "C" void kernel_launch(void* const* d_in, const int* in_sizes, int n_in,
                              void* d_out, int out_size, void* d_ws, size_t ws_size,
                              hipStream_t stream) {
  const int* X = (const int*)d_in[0];         // [1024,256] int32
  const float* Wemb = (const float*)d_in[1];  // [115,128]
  const float* Wxh = (const float*)d_in[2];   // [128,512]
  const float* Whh = (const float*)d_in[3];   // [512,512]
  const float* bh = (const float*)d_in[4];    // [512]
  const float* Why = (const float*)d_in[5];   // [512,115]
  const float* by = (const float*)d_in[6];    // [115]
  float* out = (float*)d_out;                 // [1024,115]

  char* ws = (char*)d_ws;
  float* Txh = (float*)ws;                        // 235,520 B
  _Float16* Wf = (_Float16*)(ws + 256 * 1024);    // 512 KB

  prep_table<<<dim3(V_), dim3(H_), 0, stream>>>(Wemb, Wxh, bh, Txh);
  prep_wf<<<dim3(1024), dim3(256), 0, stream>>>(Whh, Wf);
  rnn_main<<<dim3(64), dim3(1024), 0, stream>>>(X, Txh, Wf, Why, by, out);
}